// Round 5
// baseline (186.231 us; speedup 1.0000x reference)
//
#include <hip/hip_runtime.h>

// NCC loss, fused z-sweep, v5 = R1 sync structure + DS-op reduction:
//  - xf reads window as 5 aligned float4 (10 pts, subtract extra): 108->60 ops
//  - sliding-window y-filter (128 thr x 4 outputs): 144->80 ops
// Single-buffered LDS (32.5 KB), 3 uniform barriers/slice.
// Tile 32(x) x 16(y), z-chunk 20, halo 4 (KS=9). Grid 800 x 512.

#define TX 32
#define TY 16
#define ZC 20
#define PH 24          // TY+8
#define PW 40          // TX+8
#define NSTEP 28       // ZC+8
#define NN 160
#define NPLANE (160*160)

__global__ void ncc_zero_ws(float* ws) { ws[0] = 0.0f; }

__global__ __launch_bounds__(512, 3)
void ncc_fused(const float* __restrict__ pred, const float* __restrict__ target,
               float* __restrict__ ws) {
  __shared__ float2 st[PH * PW];      // staged (t,p)          7.5 KB
  __shared__ float4 xf4[PH * TX];     // x-filt (t,p,t2,p2)   12.0 KB
  __shared__ float  xf1[PH * TX];     // x-filt tp             3.0 KB
  __shared__ float4 yf4[TY * TX];     // xy-filt (t,p,t2,p2)   8.0 KB
  __shared__ float  yf1[TY * TX];     // xy-filt tp            2.0 KB
  __shared__ float  wsum[8];

  const int tid = threadIdx.x;
  const int tx = tid & 31;
  const int ty = tid >> 5;            // 0..15

  int b = blockIdx.x;
  const int xt = b % 5;  b /= 5;
  const int yt = b % 10; b /= 10;
  const int zc = b % 8;  b /= 8;
  const int x0 = xt * TX, y0 = yt * TY, z0 = zc * ZC;
  const size_t bbase = (size_t)b * (size_t)NN * (size_t)NPLANE;

  float buf[5][9];
  float run0 = 0, run1 = 0, run2 = 0, run3 = 0, run4 = 0;
  #pragma unroll
  for (int f = 0; f < 5; ++f)
    #pragma unroll
    for (int j = 0; j < 9; ++j) buf[f][j] = 0.0f;
  float acc = 0.0f;
  const float inv_kvol = 1.0f / 729.0f;

  for (int s0 = 0; s0 < NSTEP; s0 += 9) {
    #pragma unroll
    for (int pp = 0; pp < 9; ++pp) {
      const int s = s0 + pp;
      if (s < NSTEP) {
        const int zi = z0 - 4 + s;
        const bool zvalid = ((unsigned)zi < NN);   // block-uniform
        float cur0 = 0, cur1 = 0, cur2 = 0, cur3 = 0, cur4 = 0;
        if (zvalid) {
          // ---- phase 1: stage slice (zero-pad x,y) ----
          const size_t zb = bbase + (size_t)zi * (size_t)NPLANE;
          for (int pos = tid; pos < PH * PW; pos += 512) {
            const int yy = pos / PW, xx = pos - yy * PW;
            const int gy = y0 + yy - 4, gx = x0 + xx - 4;
            float tv = 0.0f, pv = 0.0f;
            if ((unsigned)gy < NN && (unsigned)gx < NN) {
              const size_t idx = zb + (size_t)(gy * NN + gx);
              tv = target[idx];
              pv = pred[idx];
            }
            st[pos] = make_float2(tv, pv);
          }
          __syncthreads();   // A
          // ---- phase 2: x-filter via 5 aligned float4 reads (10 pts - 1) ----
          for (int pos = tid; pos < PH * TX; pos += 512) {
            const int yy = pos >> 5;
            const int xx = pos & 31;
            const int xe = xx & ~1;
            const float4* base = (const float4*)&st[yy * PW + xe];
            const float4 q0 = base[0];
            const float4 q1 = base[1];
            const float4 q2 = base[2];
            const float4 q3 = base[3];
            const float4 q4 = base[4];
            float s_t = 0, s_p = 0, s_t2 = 0, s_p2 = 0, s_tp = 0;
            #define ACCPT(T, P)                                               \
              { s_t += (T); s_p += (P);                                       \
                s_t2 = fmaf((T), (T), s_t2);                                  \
                s_p2 = fmaf((P), (P), s_p2);                                  \
                s_tp = fmaf((T), (P), s_tp); }
            ACCPT(q0.x, q0.y) ACCPT(q0.z, q0.w)
            ACCPT(q1.x, q1.y) ACCPT(q1.z, q1.w)
            ACCPT(q2.x, q2.y) ACCPT(q2.z, q2.w)
            ACCPT(q3.x, q3.y) ACCPT(q3.z, q3.w)
            ACCPT(q4.x, q4.y) ACCPT(q4.z, q4.w)
            #undef ACCPT
            const bool odd = (xx & 1);
            const float et = odd ? q0.x : q4.z;
            const float ep = odd ? q0.y : q4.w;
            s_t -= et; s_p -= ep;
            s_t2 = fmaf(-et, et, s_t2);
            s_p2 = fmaf(-ep, ep, s_p2);
            s_tp = fmaf(-et, ep, s_tp);
            xf4[pos] = make_float4(s_t, s_p, s_t2, s_p2);
            xf1[pos] = s_tp;
          }
          __syncthreads();   // B
          // ---- phase 3: sliding y-filter (128 threads, 4 outputs each) ----
          if (tid < 128) {
            const int yx = tid & 31;
            const int r0 = (tid >> 5) * 4;    // 0,4,8,12
            float w0 = 0, w1 = 0, w2 = 0, w3 = 0, w4 = 0;
            #pragma unroll
            for (int k = 0; k < 9; ++k) {
              const float4 a = xf4[(r0 + k) * TX + yx];
              const float  c = xf1[(r0 + k) * TX + yx];
              w0 += a.x; w1 += a.y; w2 += a.z; w3 += a.w; w4 += c;
            }
            yf4[r0 * TX + yx] = make_float4(w0, w1, w2, w3);
            yf1[r0 * TX + yx] = w4;
            #pragma unroll
            for (int k = 0; k < 3; ++k) {
              const float4 an = xf4[(r0 + 9 + k) * TX + yx];
              const float  cn = xf1[(r0 + 9 + k) * TX + yx];
              const float4 ao = xf4[(r0 + k) * TX + yx];
              const float  co = xf1[(r0 + k) * TX + yx];
              w0 += an.x - ao.x; w1 += an.y - ao.y;
              w2 += an.z - ao.z; w3 += an.w - ao.w; w4 += cn - co;
              yf4[(r0 + 1 + k) * TX + yx] = make_float4(w0, w1, w2, w3);
              yf1[(r0 + 1 + k) * TX + yx] = w4;
            }
          }
          __syncthreads();   // C
          // ---- phase 4: owner reads its xy-filtered moments ----
          {
            const float4 a = yf4[ty * TX + tx];
            const float  c = yf1[ty * TX + tx];
            cur0 = a.x; cur1 = a.y; cur2 = a.z; cur3 = a.w; cur4 = c;
          }
        }
        // ---- z running window + NCC (slot pp is compile-time static) ----
        run0 += cur0 - buf[0][pp]; buf[0][pp] = cur0;
        run1 += cur1 - buf[1][pp]; buf[1][pp] = cur1;
        run2 += cur2 - buf[2][pp]; buf[2][pp] = cur2;
        run3 += cur3 - buf[3][pp]; buf[3][pp] = cur3;
        run4 += cur4 - buf[4][pp]; buf[4][pp] = cur4;
        if (s >= 8) {
          const float tavg = run0 * inv_kvol;
          const float pavg = run1 * inv_kvol;
          const float cross = run4 - pavg * run0;
          const float tvar  = run2 - tavg * run0;
          const float pvar  = run3 - pavg * run1;
          acc += (cross * cross) / (tvar * pvar + 1e-5f);
        }
      }
    }
  }

  // ---- reduction: wave shuffle -> LDS -> one atomicAdd per block ----
  #pragma unroll
  for (int off = 32; off > 0; off >>= 1)
    acc += __shfl_down(acc, off, 64);
  if ((tid & 63) == 0) wsum[tid >> 6] = acc;
  __syncthreads();
  if (tid == 0) {
    float tot = 0.0f;
    #pragma unroll
    for (int w = 0; w < 8; ++w) tot += wsum[w];
    atomicAdd(ws, tot);
  }
}

__global__ void ncc_finalize(const float* __restrict__ ws, float* __restrict__ out) {
  out[0] = -ws[0] * (1.0f / 8192000.0f);
}

extern "C" void kernel_launch(void* const* d_in, const int* in_sizes, int n_in,
                              void* d_out, int out_size, void* d_ws, size_t ws_size,
                              hipStream_t stream) {
  const float* pred   = (const float*)d_in[0];
  const float* target = (const float*)d_in[1];
  float* out = (float*)d_out;
  float* ws  = (float*)d_ws;

  ncc_zero_ws<<<1, 1, 0, stream>>>(ws);
  ncc_fused<<<800, 512, 0, stream>>>(pred, target, ws);
  ncc_finalize<<<1, 1, 0, stream>>>(ws, out);
}